// Round 7
// baseline (646.729 us; speedup 1.0000x reference)
//
#include <hip/hip_runtime.h>

#define BB 8192
#define TT 20
#define HH 128
#define H4 512
#define KC 5
#define R 32
#define NT 512
#define NBLK (BB/R)   // 256 blocks = 1 per CU

typedef _Float16 f16;
typedef float v4f __attribute__((ext_vector_type(4)));
typedef _Float16 v8h __attribute__((ext_vector_type(8)));
typedef _Float16 v4h __attribute__((ext_vector_type(4)));

// output segment offsets (elements)
#define GY_OFF (BB*TT*30)
#define GF_OFF (GY_OFF + BB*TT*15)
#define GFA_OFF (GF_OFF + BB*TT*15)

// ws offsets in f16 units
#define UMY_O   0          // U_my fp16 hi, permuted cols (65536)
#define UFF_O   65536
#define WMYH_O  131072     // W_my[:128] fp16 hi, permuted (65536)
#define WMYL_O  196608     // fp16 lo
#define WFFH_O  262144
#define WFFL_O  327680
#define WHMY_O  393216     // Wh_my hi (6144)
#define WHFF_O  399360     // Wh_ff hi (4096)
#define PREP_N  272384

__device__ __forceinline__ float sigm(float x){ return 1.0f / (1.0f + __expf(-x)); }
__device__ __forceinline__ float tanh_(float x){
    x = fminf(10.0f, fmaxf(-10.0f, x));
    float e = __expf(2.0f * x);
    return (e - 1.0f) / (e + 1.0f);
}

#define AM0 0.3f
#define AM1 0.1f
#define AO  0.3f

// B-frag (16x16x32): lane L holds B[k=(L>>4)*8+jj][n=L&15], jj=0..7.
// col permutation for U/W: tile c -> gate=c&3, unit base=((c>>2)<<4).
__global__ void prep_kernel(const float* __restrict__ U_my, const float* __restrict__ U_ff,
                            const float* __restrict__ W_my, const float* __restrict__ W_ff,
                            const float* __restrict__ Wh_my, const float* __restrict__ Wh_ff,
                            f16* __restrict__ ws)
{
    int t = blockIdx.x * 256 + threadIdx.x;
    if (t >= PREP_N) return;
    if (t < 131072){
        int m = t >> 16, e = t & 65535;
        int jj = e & 7, L = (e >> 3) & 63, q = (e >> 9) & 3, c = e >> 11;
        int k   = q*32 + ((L >> 4) << 3) + jj;
        int col = (c & 3)*HH + ((c >> 2) << 4) + (L & 15);
        float v = (m ? U_ff : U_my)[k*H4 + col];
        ws[(m ? UFF_O : UMY_O) + e] = (f16)v;
    } else if (t < 262144){
        int m = (t - 131072) >> 16, e = t & 65535;
        int jj = e & 7, L = (e >> 3) & 63, q = (e >> 9) & 3, c = e >> 11;
        int k   = q*32 + ((L >> 4) << 3) + jj;
        int col = (c & 3)*HH + ((c >> 2) << 4) + (L & 15);
        float v = (m ? W_ff : W_my)[k*H4 + col];
        f16 hi = (f16)v;
        f16 lo = (f16)(v - (float)hi);
        ws[(m ? WFFH_O : WMYH_O) + e] = hi;
        ws[(m ? WFFL_O : WMYL_O) + e] = lo;
    } else if (t < 262144 + 6144){
        int e = t - 262144;
        int jj = e & 7, L = (e >> 3) & 63, q = (e >> 9) & 3, c = e >> 11;   // c 0..2
        int k   = q*32 + ((L >> 4) << 3) + jj;
        int col = (c << 4) + (L & 15);
        float v = (col < 45) ? Wh_my[k*45 + col] : 0.0f;
        ws[WHMY_O + e] = (f16)v;
    } else {
        int e = t - 262144 - 6144;
        int jj = e & 7, L = (e >> 3) & 63, q = (e >> 9) & 3, c = e >> 11;   // c 0..1
        int k   = q*32 + ((L >> 4) << 3) + jj;
        int col = (c << 4) + (L & 15);
        float v = (col < 30) ? Wh_ff[k*30 + col] : 0.0f;
        ws[WHFF_O + e] = (f16)v;
    }
}

__global__ __launch_bounds__(NT, 2) void decoder_kernel(
    const float* __restrict__ cond_m, const float* __restrict__ cond_y,
    const float* __restrict__ cond_f, const float* __restrict__ cond_fa,
    const float* __restrict__ state_h, const float* __restrict__ state_c,
    const float* __restrict__ W_my, const float* __restrict__ b_my,
    const float* __restrict__ W_ff, const float* __restrict__ b_ff,
    const float* __restrict__ bh_my, const float* __restrict__ bh_ff,
    const float* __restrict__ gum, const float* __restrict__ znorm,
    const f16* __restrict__ ws, float* __restrict__ out)
{
    __shared__ f16 s_hm_hi[R][136], s_hm_lo[R][136];
    __shared__ f16 s_hf_hi[R][136], s_hf_lo[R][136];
    __shared__ float s_wcm[5][H4], s_wcf[2][H4];
    __shared__ float s_r[R][76];
    __shared__ float s_red[R][8];
    __shared__ float s_c5[R][5], s_c2[R][2];
    __shared__ float s_znc[R][10];    // zn[0..4], next-cond[5..9]

    const int tid  = threadIdx.x;
    const int lane = tid & 63, w = tid >> 6;
    const int quad = lane >> 4, l15 = lane & 15;
    const int jcol = (w << 4) + l15;
    const int row0 = blockIdx.x * R;

    // ---- init LDS ----
    for (int p = tid; p < R*HH; p += NT){
        int r = p >> 7, k = p & 127;
        float v = state_h[(row0 + r)*HH + k];
        f16 hi = (f16)v, lo = (f16)(v - (float)hi);
        s_hm_hi[r][k] = hi; s_hm_lo[r][k] = lo;
        s_hf_hi[r][k] = hi; s_hf_lo[r][k] = lo;
    }
    for (int p = tid; p < 5*H4; p += NT) s_wcm[p >> 9][p & 511] = W_my[(HH + (p >> 9))*H4 + (p & 511)];
    for (int p = tid; p < 2*H4; p += NT) s_wcf[p >> 9][p & 511] = W_ff[(HH + (p >> 9))*H4 + (p & 511)];
    if (tid < R){
        int b = row0 + tid;
        float m0 = cond_m[(b*TT)*2 + 0], m1 = cond_m[(b*TT)*2 + 1];
        float y0 = cond_y[b*TT], f0 = cond_f[b*TT], fa0 = cond_fa[b*TT];
        s_c5[tid][0]=m0; s_c5[tid][1]=m1; s_c5[tid][2]=y0; s_c5[tid][3]=f0; s_c5[tid][4]=fa0;
        s_c2[tid][0]=f0; s_c2[tid][1]=fa0;
    }
    float c_my[8], c_ff[8];
    #pragma unroll
    for (int rt = 0; rt < 2; rt++)
        #pragma unroll
        for (int v = 0; v < 4; v++){
            int row = rt*16 + quad*4 + v;
            float cv = state_c[(row0 + row)*HH + jcol];
            c_my[rt*4+v] = cv; c_ff[rt*4+v] = cv;
        }
    __syncthreads();

    // ---- one-time: pre = enc_h @ W[:128] + b (3-term fp16 MFMA), pack to fp16 ----
    v4h pm_pk[4][2], pf_pk[4][2];
    #pragma unroll
    for (int ci = 0; ci < 4; ci++){
        v4f prm[2], prf[2];
        #pragma unroll
        for (int rt = 0; rt < 2; rt++){ prm[rt] = (v4f){0,0,0,0}; prf[rt] = (v4f){0,0,0,0}; }
        #pragma unroll
        for (int q = 0; q < 4; q++){
            int off = ((w*16 + ci*4 + q)*64 + lane)*8;
            v8h bmh = *(const v8h*)(ws + WMYH_O + off);
            v8h bml = *(const v8h*)(ws + WMYL_O + off);
            v8h bfh = *(const v8h*)(ws + WFFH_O + off);
            v8h bfl = *(const v8h*)(ws + WFFL_O + off);
            #pragma unroll
            for (int rt = 0; rt < 2; rt++){
                v8h ahi = *(const v8h*)&s_hm_hi[rt*16 + l15][q*32 + quad*8];
                v8h alo = *(const v8h*)&s_hm_lo[rt*16 + l15][q*32 + quad*8];
                prm[rt] = __builtin_amdgcn_mfma_f32_16x16x32_f16(ahi, bmh, prm[rt],0,0,0);
                prm[rt] = __builtin_amdgcn_mfma_f32_16x16x32_f16(ahi, bml, prm[rt],0,0,0);
                prm[rt] = __builtin_amdgcn_mfma_f32_16x16x32_f16(alo, bmh, prm[rt],0,0,0);
                prf[rt] = __builtin_amdgcn_mfma_f32_16x16x32_f16(ahi, bfh, prf[rt],0,0,0);
                prf[rt] = __builtin_amdgcn_mfma_f32_16x16x32_f16(ahi, bfl, prf[rt],0,0,0);
                prf[rt] = __builtin_amdgcn_mfma_f32_16x16x32_f16(alo, bfh, prf[rt],0,0,0);
            }
        }
        float bmv = b_my[ci*HH + jcol], bfv = b_ff[ci*HH + jcol];
        #pragma unroll
        for (int rt = 0; rt < 2; rt++){
            #pragma unroll
            for (int v = 0; v < 4; v++){
                pm_pk[ci][rt][v] = (f16)(prm[rt][v] + bmv);
                pf_pk[ci][rt][v] = (f16)(prf[rt][v] + bfv);
            }
        }
    }

    // ---- persistent U_my B-fragments ----
    v8h BUm[4][4];
    #pragma unroll
    for (int ci = 0; ci < 4; ci++)
        #pragma unroll
        for (int q = 0; q < 4; q++)
            BUm[ci][q] = *(const v8h*)(ws + UMY_O + ((w*16 + ci*4 + q)*64 + lane)*8);

    // head constants for this wave
    const int hch   = (w < 3) ? w : w - 3;
    const int hgc   = hch*16 + l15;
    const int hncol = (w < 3) ? 45 : 30;
    const int hrb   = (w < 3) ? 0 : 45;
    const int hbase = (w < 3) ? WHMY_O : WHFF_O;
    float hbias = 0.f;
    if (w < 5 && hgc < hncol) hbias = (w < 3) ? bh_my[hgc] : bh_ff[hgc];

    for (int t = 0; t < TT; t++){
        // =================== Phase A ===================
        // prefetch sampling data for step t-1
        float gv[5];
        if (t > 0 && tid < 128){
            int r = tid >> 2, g = tid & 3, b = row0 + r;
            const float* gp = gum + (((t-1)*4 + g)*BB + b)*KC;
            #pragma unroll
            for (int k = 0; k < KC; k++) gv[k] = gp[k];
        }
        float pv = 0.f; int pr = 0, pfld = 0;
        if (t > 0 && tid >= 128 && tid < 448){
            int idx = tid - 128;
            pr = idx / 10; pfld = idx % 10;
            int b = row0 + pr;
            if (pfld < 5)      pv = znorm[((t-1)*BB + b)*5 + pfld];
            else if (pfld == 5) pv = cond_m[(b*TT + t)*2 + 0];
            else if (pfld == 6) pv = cond_m[(b*TT + t)*2 + 1];
            else if (pfld == 7) pv = cond_y[b*TT + t];
            else if (pfld == 8) pv = cond_f[b*TT + t];
            else                pv = cond_fa[b*TT + t];
        }

        v4f zm[2][4], zf[2][4];
        #pragma unroll
        for (int ci = 0; ci < 4; ci++)
            #pragma unroll
            for (int rt = 0; rt < 2; rt++){
                zm[rt][ci] = (v4f){(float)pm_pk[ci][rt][0], (float)pm_pk[ci][rt][1],
                                   (float)pm_pk[ci][rt][2], (float)pm_pk[ci][rt][3]};
                zf[rt][ci] = (v4f){(float)pf_pk[ci][rt][0], (float)pf_pk[ci][rt][1],
                                   (float)pf_pk[ci][rt][2], (float)pf_pk[ci][rt][3]};
            }
        v4f hacc[2] = {(v4f){0,0,0,0}, (v4f){0,0,0,0}};

        #pragma unroll
        for (int q = 0; q < 4; q++){
            v8h bf0 = *(const v8h*)(ws + UFF_O + ((w*16 + 0*4 + q)*64 + lane)*8);
            v8h bf1 = *(const v8h*)(ws + UFF_O + ((w*16 + 1*4 + q)*64 + lane)*8);
            v8h bf2 = *(const v8h*)(ws + UFF_O + ((w*16 + 2*4 + q)*64 + lane)*8);
            v8h bf3 = *(const v8h*)(ws + UFF_O + ((w*16 + 3*4 + q)*64 + lane)*8);
            v8h bh;
            if (w < 5) bh = *(const v8h*)(ws + hbase + ((hch*4 + q)*64 + lane)*8);
            #pragma unroll
            for (int rt = 0; rt < 2; rt++){
                v8h ahm = *(const v8h*)&s_hm_hi[rt*16 + l15][q*32 + quad*8];
                v8h alm = *(const v8h*)&s_hm_lo[rt*16 + l15][q*32 + quad*8];
                v8h ahf = *(const v8h*)&s_hf_hi[rt*16 + l15][q*32 + quad*8];
                v8h alf = *(const v8h*)&s_hf_lo[rt*16 + l15][q*32 + quad*8];
                zm[rt][0] = __builtin_amdgcn_mfma_f32_16x16x32_f16(ahm, BUm[0][q], zm[rt][0],0,0,0);
                zm[rt][1] = __builtin_amdgcn_mfma_f32_16x16x32_f16(ahm, BUm[1][q], zm[rt][1],0,0,0);
                zm[rt][2] = __builtin_amdgcn_mfma_f32_16x16x32_f16(ahm, BUm[2][q], zm[rt][2],0,0,0);
                zm[rt][3] = __builtin_amdgcn_mfma_f32_16x16x32_f16(ahm, BUm[3][q], zm[rt][3],0,0,0);
                zm[rt][0] = __builtin_amdgcn_mfma_f32_16x16x32_f16(alm, BUm[0][q], zm[rt][0],0,0,0);
                zm[rt][1] = __builtin_amdgcn_mfma_f32_16x16x32_f16(alm, BUm[1][q], zm[rt][1],0,0,0);
                zm[rt][2] = __builtin_amdgcn_mfma_f32_16x16x32_f16(alm, BUm[2][q], zm[rt][2],0,0,0);
                zm[rt][3] = __builtin_amdgcn_mfma_f32_16x16x32_f16(alm, BUm[3][q], zm[rt][3],0,0,0);
                zf[rt][0] = __builtin_amdgcn_mfma_f32_16x16x32_f16(ahf, bf0, zf[rt][0],0,0,0);
                zf[rt][1] = __builtin_amdgcn_mfma_f32_16x16x32_f16(ahf, bf1, zf[rt][1],0,0,0);
                zf[rt][2] = __builtin_amdgcn_mfma_f32_16x16x32_f16(ahf, bf2, zf[rt][2],0,0,0);
                zf[rt][3] = __builtin_amdgcn_mfma_f32_16x16x32_f16(ahf, bf3, zf[rt][3],0,0,0);
                zf[rt][0] = __builtin_amdgcn_mfma_f32_16x16x32_f16(alf, bf0, zf[rt][0],0,0,0);
                zf[rt][1] = __builtin_amdgcn_mfma_f32_16x16x32_f16(alf, bf1, zf[rt][1],0,0,0);
                zf[rt][2] = __builtin_amdgcn_mfma_f32_16x16x32_f16(alf, bf2, zf[rt][2],0,0,0);
                zf[rt][3] = __builtin_amdgcn_mfma_f32_16x16x32_f16(alf, bf3, zf[rt][3],0,0,0);
                if (w < 5 && t > 0)
                    hacc[rt] = __builtin_amdgcn_mfma_f32_16x16x32_f16(
                        (w < 3) ? ahm : ahf, bh, hacc[rt],0,0,0);
            }
        }
        // heads(t-1) -> s_r
        if (w < 5 && t > 0 && hgc < hncol){
            #pragma unroll
            for (int rt = 0; rt < 2; rt++)
                #pragma unroll
                for (int v = 0; v < 4; v++)
                    s_r[rt*16 + quad*4 + v][hrb + hgc] = hacc[rt][v] + hbias;
        }
        // commit prefetched zn/cond
        if (t > 0 && tid >= 128 && tid < 448) s_znc[pr][pfld] = pv;
        __syncthreads();

        // =================== Phase B: softmax + sample + clip (step t-1) ===================
        if (t > 0 && tid < 128){
            int r = tid >> 2, g = tid & 3;
            int base = (g==0) ? 0 : (g==1) ? 30 : (g==2) ? 45 : 60;
            const float* Rr = s_r[r];
            float l0 = Rr[base], l1 = Rr[base+1], l2 = Rr[base+2], l3 = Rr[base+3], l4 = Rr[base+4];
            float m = fmaxf(fmaxf(fmaxf(l0,l1), fmaxf(l2,l3)), l4);
            float s = __expf(l0-m)+__expf(l1-m)+__expf(l2-m)+__expf(l3-m)+__expf(l4-m);
            s_red[r][2*g] = m; s_red[r][2*g+1] = 1.0f / s;
            int idx = 0; float bv = l0 + gv[0];
            { float v1 = l1+gv[1]; if (v1>bv){bv=v1;idx=1;}
              float v2 = l2+gv[2]; if (v2>bv){bv=v2;idx=2;}
              float v3 = l3+gv[3]; if (v3>bv){bv=v3;idx=3;}
              float v4 = l4+gv[4]; if (v4>bv){bv=v4;idx=4;} }
            float mu = Rr[base+5+idx], sd = __expf(Rr[base+10+idx]);
            if (g == 0){
                float z1 = s_znc[r][0], z2 = s_znc[r][1];
                float rv = tanh_(Rr[25+idx]);
                float slon = mu + sd*z1;
                float slat = Rr[15+idx] + __expf(Rr[20+idx]) *
                             (rv*z1 + sqrtf(fmaxf(0.f, 1.f - rv*rv))*z2);
                float nm0 = s_znc[r][5], nm1 = s_znc[r][6];
                s_c5[r][0] = (fabsf(slon-nm0) < AM0) ? slon : nm0;
                s_c5[r][1] = (fabsf(slat-nm1) < AM1) ? slat : nm1;
            } else {
                float zz = s_znc[r][1+g];
                float sv = mu + sd*zz;
                float nv = s_znc[r][6+g];
                float cv = (fabsf(sv-nv) < AO) ? sv : nv;
                if (g == 1) s_c5[r][2] = cv;
                else if (g == 2){ s_c5[r][3] = cv; s_c2[r][0] = cv; }
                else            { s_c5[r][4] = cv; s_c2[r][1] = cv; }
            }
        }
        __syncthreads();

        // =================== Phase C: gates(t) + outputs(t-1) ===================
        #pragma unroll
        for (int rt = 0; rt < 2; rt++)
            #pragma unroll
            for (int v = 0; v < 4; v++){
                int row = rt*16 + quad*4 + v;
                float z0 = zm[rt][0][v], z1 = zm[rt][1][v], z2 = zm[rt][2][v], z3 = zm[rt][3][v];
                #pragma unroll
                for (int k = 0; k < 5; k++){
                    float cv = s_c5[row][k];
                    z0 = fmaf(cv, s_wcm[k][0*HH + jcol], z0);
                    z1 = fmaf(cv, s_wcm[k][1*HH + jcol], z1);
                    z2 = fmaf(cv, s_wcm[k][2*HH + jcol], z2);
                    z3 = fmaf(cv, s_wcm[k][3*HH + jcol], z3);
                }
                float c2 = sigm(z1)*c_my[rt*4+v] + sigm(z0)*tanh_(z2);
                c_my[rt*4+v] = c2;
                float h = sigm(z3)*tanh_(c2);
                f16 hi = (f16)h;
                s_hm_hi[row][jcol] = hi;
                s_hm_lo[row][jcol] = (f16)(h - (float)hi);

                float y0 = zf[rt][0][v], y1 = zf[rt][1][v], y2 = zf[rt][2][v], y3 = zf[rt][3][v];
                #pragma unroll
                for (int k = 0; k < 2; k++){
                    float cv = s_c2[row][k];
                    y0 = fmaf(cv, s_wcf[k][0*HH + jcol], y0);
                    y1 = fmaf(cv, s_wcf[k][1*HH + jcol], y1);
                    y2 = fmaf(cv, s_wcf[k][2*HH + jcol], y2);
                    y3 = fmaf(cv, s_wcf[k][3*HH + jcol], y3);
                }
                float d2 = sigm(y1)*c_ff[rt*4+v] + sigm(y0)*tanh_(y2);
                c_ff[rt*4+v] = d2;
                float hf = sigm(y3)*tanh_(d2);
                f16 hif = (f16)hf;
                s_hf_hi[row][jcol] = hif;
                s_hf_lo[row][jcol] = (f16)(hf - (float)hif);
            }

        if (t > 0){
            int tp = t - 1;
            for (int idx = tid; idx < R*75; idx += NT){
                int r = idx / 75, q = idx % 75;
                int b = row0 + r;
                float v; int dst;
                if (q < 30){
                    float x = s_r[r][q];
                    if (q < 5)       v = __expf(x - s_red[r][0]) * s_red[r][1];
                    else if (q < 10) v = x;
                    else if (q < 15) v = __expf(x);
                    else if (q < 20) v = x;
                    else if (q < 25) v = __expf(x);
                    else             v = tanh_(x);
                    dst = (b*TT + tp)*30 + q;
                } else if (q < 45){
                    int q2 = q - 30; float x = s_r[r][30 + q2];
                    v = (q2 < 5) ? __expf(x - s_red[r][2]) * s_red[r][3]
                                 : (q2 < 10) ? x : __expf(x);
                    dst = GY_OFF + (b*TT + tp)*15 + q2;
                } else if (q < 60){
                    int q2 = q - 45; float x = s_r[r][45 + q2];
                    v = (q2 < 5) ? __expf(x - s_red[r][4]) * s_red[r][5]
                                 : (q2 < 10) ? x : __expf(x);
                    dst = GF_OFF + (b*TT + tp)*15 + q2;
                } else {
                    int q2 = q - 60; float x = s_r[r][60 + q2];
                    v = (q2 < 5) ? __expf(x - s_red[r][6]) * s_red[r][7]
                                 : (q2 < 10) ? x : __expf(x);
                    dst = GFA_OFF + (b*TT + tp)*15 + q2;
                }
                out[dst] = v;
            }
        }
        __syncthreads();
    }

    // =================== Epilogue: heads(TT-1) + softmax + outputs ===================
    {
        v4f hacc[2] = {(v4f){0,0,0,0}, (v4f){0,0,0,0}};
        if (w < 5){
            #pragma unroll
            for (int q = 0; q < 4; q++){
                v8h bh = *(const v8h*)(ws + hbase + ((hch*4 + q)*64 + lane)*8);
                #pragma unroll
                for (int rt = 0; rt < 2; rt++){
                    v8h a = (w < 3) ? *(const v8h*)&s_hm_hi[rt*16 + l15][q*32 + quad*8]
                                    : *(const v8h*)&s_hf_hi[rt*16 + l15][q*32 + quad*8];
                    hacc[rt] = __builtin_amdgcn_mfma_f32_16x16x32_f16(a, bh, hacc[rt],0,0,0);
                }
            }
            if (hgc < hncol){
                #pragma unroll
                for (int rt = 0; rt < 2; rt++)
                    #pragma unroll
                    for (int v = 0; v < 4; v++)
                        s_r[rt*16 + quad*4 + v][hrb + hgc] = hacc[rt][v] + hbias;
            }
        }
        __syncthreads();
        if (tid < 128){
            int r = tid >> 2, g = tid & 3;
            int base = (g==0) ? 0 : (g==1) ? 30 : (g==2) ? 45 : 60;
            float m = s_r[r][base];
            #pragma unroll
            for (int k = 1; k < KC; k++) m = fmaxf(m, s_r[r][base+k]);
            float s = 0.f;
            #pragma unroll
            for (int k = 0; k < KC; k++) s += __expf(s_r[r][base+k] - m);
            s_red[r][2*g] = m; s_red[r][2*g+1] = 1.0f / s;
        }
        __syncthreads();
        int tp = TT - 1;
        for (int idx = tid; idx < R*75; idx += NT){
            int r = idx / 75, q = idx % 75;
            int b = row0 + r;
            float v; int dst;
            if (q < 30){
                float x = s_r[r][q];
                if (q < 5)       v = __expf(x - s_red[r][0]) * s_red[r][1];
                else if (q < 10) v = x;
                else if (q < 15) v = __expf(x);
                else if (q < 20) v = x;
                else if (q < 25) v = __expf(x);
                else             v = tanh_(x);
                dst = (b*TT + tp)*30 + q;
            } else if (q < 45){
                int q2 = q - 30; float x = s_r[r][30 + q2];
                v = (q2 < 5) ? __expf(x - s_red[r][2]) * s_red[r][3]
                             : (q2 < 10) ? x : __expf(x);
                dst = GY_OFF + (b*TT + tp)*15 + q2;
            } else if (q < 60){
                int q2 = q - 45; float x = s_r[r][45 + q2];
                v = (q2 < 5) ? __expf(x - s_red[r][4]) * s_red[r][5]
                             : (q2 < 10) ? x : __expf(x);
                dst = GF_OFF + (b*TT + tp)*15 + q2;
            } else {
                int q2 = q - 60; float x = s_r[r][60 + q2];
                v = (q2 < 5) ? __expf(x - s_red[r][6]) * s_red[r][7]
                             : (q2 < 10) ? x : __expf(x);
                dst = GFA_OFF + (b*TT + tp)*15 + q2;
            }
            out[dst] = v;
        }
    }
}

extern "C" void kernel_launch(void* const* d_in, const int* in_sizes, int n_in,
                              void* d_out, int out_size, void* d_ws, size_t ws_size,
                              hipStream_t stream)
{
    (void)in_sizes; (void)n_in; (void)ws_size; (void)out_size;
    const float* cond_m  = (const float*)d_in[0];
    const float* cond_y  = (const float*)d_in[1];
    const float* cond_f  = (const float*)d_in[2];
    const float* cond_fa = (const float*)d_in[3];
    const float* state_h = (const float*)d_in[4];
    const float* state_c = (const float*)d_in[5];
    const float* W_my    = (const float*)d_in[6];
    const float* U_my    = (const float*)d_in[7];
    const float* b_my    = (const float*)d_in[8];
    const float* W_ff    = (const float*)d_in[9];
    const float* U_ff    = (const float*)d_in[10];
    const float* b_ff    = (const float*)d_in[11];
    const float* Wh_my   = (const float*)d_in[12];
    const float* bh_my   = (const float*)d_in[13];
    const float* Wh_ff   = (const float*)d_in[14];
    const float* bh_ff   = (const float*)d_in[15];
    const float* gum     = (const float*)d_in[16];
    const float* znorm   = (const float*)d_in[17];
    f16* ws = (f16*)d_ws;
    float* out = (float*)d_out;

    prep_kernel<<<(PREP_N + 255)/256, 256, 0, stream>>>(U_my, U_ff, W_my, W_ff, Wh_my, Wh_ff, ws);
    decoder_kernel<<<NBLK, NT, 0, stream>>>(
        cond_m, cond_y, cond_f, cond_fa, state_h, state_c,
        W_my, b_my, W_ff, b_ff, bh_my, bh_ff, gum, znorm, ws, out);
}

// Round 8
// 590.981 us; speedup vs baseline: 1.0943x; 1.0943x over previous
//
#include <hip/hip_runtime.h>

#define BB 8192
#define TT 20
#define HH 128
#define H4 512
#define KC 5
#define R 32
#define NT 512
#define NBLK (BB/R)   // 256 blocks = 1 per CU

typedef _Float16 f16;
typedef float v4f __attribute__((ext_vector_type(4)));
typedef _Float16 v8h __attribute__((ext_vector_type(8)));
typedef _Float16 v4h __attribute__((ext_vector_type(4)));

// output segment offsets (elements)
#define GY_OFF (BB*TT*30)
#define GF_OFF (GY_OFF + BB*TT*15)
#define GFA_OFF (GF_OFF + BB*TT*15)

// ws offsets in f16 units
#define UMY_O   0          // U_my fp16 hi, permuted cols (65536)
#define UFF_O   65536
#define WMYH_O  131072     // W_my[:128] fp16 hi, permuted (65536)
#define WMYL_O  196608     // fp16 lo
#define WFFH_O  262144
#define WFFL_O  327680
#define WHMY_O  393216     // Wh_my hi (6144)
#define WHFF_O  399360     // Wh_ff hi (4096)
#define PREP_N  272384

__device__ __forceinline__ float sigm(float x){ return 1.0f / (1.0f + __expf(-x)); }
__device__ __forceinline__ float tanh_(float x){
    x = fminf(10.0f, fmaxf(-10.0f, x));
    float e = __expf(2.0f * x);
    return (e - 1.0f) / (e + 1.0f);
}

#define AM0 0.3f
#define AM1 0.1f
#define AO  0.3f

// B-frag (16x16x32): lane L holds B[k=(L>>4)*8+jj][n=L&15], jj=0..7.
// col permutation for U/W: tile c -> gate=c&3, unit base=((c>>2)<<4).
__global__ void prep_kernel(const float* __restrict__ U_my, const float* __restrict__ U_ff,
                            const float* __restrict__ W_my, const float* __restrict__ W_ff,
                            const float* __restrict__ Wh_my, const float* __restrict__ Wh_ff,
                            f16* __restrict__ ws)
{
    int t = blockIdx.x * 256 + threadIdx.x;
    if (t >= PREP_N) return;
    if (t < 131072){
        int m = t >> 16, e = t & 65535;
        int jj = e & 7, L = (e >> 3) & 63, q = (e >> 9) & 3, c = e >> 11;
        int k   = q*32 + ((L >> 4) << 3) + jj;
        int col = (c & 3)*HH + ((c >> 2) << 4) + (L & 15);
        float v = (m ? U_ff : U_my)[k*H4 + col];
        ws[(m ? UFF_O : UMY_O) + e] = (f16)v;
    } else if (t < 262144){
        int m = (t - 131072) >> 16, e = t & 65535;
        int jj = e & 7, L = (e >> 3) & 63, q = (e >> 9) & 3, c = e >> 11;
        int k   = q*32 + ((L >> 4) << 3) + jj;
        int col = (c & 3)*HH + ((c >> 2) << 4) + (L & 15);
        float v = (m ? W_ff : W_my)[k*H4 + col];
        f16 hi = (f16)v;
        f16 lo = (f16)(v - (float)hi);
        ws[(m ? WFFH_O : WMYH_O) + e] = hi;
        ws[(m ? WFFL_O : WMYL_O) + e] = lo;
    } else if (t < 262144 + 6144){
        int e = t - 262144;
        int jj = e & 7, L = (e >> 3) & 63, q = (e >> 9) & 3, c = e >> 11;   // c 0..2
        int k   = q*32 + ((L >> 4) << 3) + jj;
        int col = (c << 4) + (L & 15);
        float v = (col < 45) ? Wh_my[k*45 + col] : 0.0f;
        ws[WHMY_O + e] = (f16)v;
    } else {
        int e = t - 262144 - 6144;
        int jj = e & 7, L = (e >> 3) & 63, q = (e >> 9) & 3, c = e >> 11;   // c 0..1
        int k   = q*32 + ((L >> 4) << 3) + jj;
        int col = (c << 4) + (L & 15);
        float v = (col < 30) ? Wh_ff[k*30 + col] : 0.0f;
        ws[WHFF_O + e] = (f16)v;
    }
}

__global__ __launch_bounds__(NT, 2) void decoder_kernel(
    const float* __restrict__ cond_m, const float* __restrict__ cond_y,
    const float* __restrict__ cond_f, const float* __restrict__ cond_fa,
    const float* __restrict__ state_h, const float* __restrict__ state_c,
    const float* __restrict__ W_my, const float* __restrict__ b_my,
    const float* __restrict__ W_ff, const float* __restrict__ b_ff,
    const float* __restrict__ bh_my, const float* __restrict__ bh_ff,
    const float* __restrict__ gum, const float* __restrict__ znorm,
    const f16* __restrict__ ws, float* __restrict__ out)
{
    __shared__ f16 s_hm_hi[R][136], s_hm_lo[R][136];
    __shared__ f16 s_hf_hi[R][136], s_hf_lo[R][136];
    __shared__ f16 s_uffB[32768];    // U_ff tiles ci=2,3 per wave (64 KB)
    __shared__ f16 s_wh[10240];      // head B tiles: my 12, ff 8 (20 KB)
    __shared__ float s_wcm[5][H4], s_wcf[2][H4];
    __shared__ float s_r[R][76];
    __shared__ float s_red[R][8];
    __shared__ float s_c5[R][5], s_c2[R][2];
    __shared__ float s_znc[R][10];   // zn[0..4], next-cond[5..9]

    const int tid  = threadIdx.x;
    const int lane = tid & 63, w = tid >> 6;
    const int quad = lane >> 4, l15 = lane & 15;
    const int jcol = (w << 4) + l15;
    const int row0 = blockIdx.x * R;

    // ---- init LDS ----
    for (int p = tid; p < R*HH; p += NT){
        int r = p >> 7, k = p & 127;
        float v = state_h[(row0 + r)*HH + k];
        f16 hi = (f16)v, lo = (f16)(v - (float)hi);
        s_hm_hi[r][k] = hi; s_hm_lo[r][k] = lo;
        s_hf_hi[r][k] = hi; s_hf_lo[r][k] = lo;
    }
    for (int p = tid; p < 32768; p += NT){
        int lt = p >> 9, i = p & 511;
        int tt = (lt >> 3)*16 + 8 + (lt & 7);
        s_uffB[p] = ws[UFF_O + tt*512 + i];
    }
    for (int p = tid; p < 10240; p += NT)
        s_wh[p] = (p < 6144) ? ws[WHMY_O + p] : ws[WHFF_O + (p - 6144)];
    for (int p = tid; p < 5*H4; p += NT) s_wcm[p >> 9][p & 511] = W_my[(HH + (p >> 9))*H4 + (p & 511)];
    for (int p = tid; p < 2*H4; p += NT) s_wcf[p >> 9][p & 511] = W_ff[(HH + (p >> 9))*H4 + (p & 511)];
    if (tid < R){
        int b = row0 + tid;
        float m0 = cond_m[(b*TT)*2 + 0], m1 = cond_m[(b*TT)*2 + 1];
        float y0 = cond_y[b*TT], f0 = cond_f[b*TT], fa0 = cond_fa[b*TT];
        s_c5[tid][0]=m0; s_c5[tid][1]=m1; s_c5[tid][2]=y0; s_c5[tid][3]=f0; s_c5[tid][4]=fa0;
        s_c2[tid][0]=f0; s_c2[tid][1]=fa0;
    }
    float c_my[8], c_ff[8];
    #pragma unroll
    for (int rt = 0; rt < 2; rt++)
        #pragma unroll
        for (int v = 0; v < 4; v++){
            int row = rt*16 + quad*4 + v;
            float cv = state_c[(row0 + row)*HH + jcol];
            c_my[rt*4+v] = cv; c_ff[rt*4+v] = cv;
        }
    __syncthreads();

    // ---- one-time: pre = enc_h @ W[:128] + b (3-term fp16 MFMA), pack to fp16 ----
    v4h pm_pk[4][2], pf_pk[4][2];
    #pragma unroll
    for (int ci = 0; ci < 4; ci++){
        v4f prm[2], prf[2];
        #pragma unroll
        for (int rt = 0; rt < 2; rt++){ prm[rt] = (v4f){0,0,0,0}; prf[rt] = (v4f){0,0,0,0}; }
        #pragma unroll
        for (int q = 0; q < 4; q++){
            int off = ((w*16 + ci*4 + q)*64 + lane)*8;
            v8h bmh = *(const v8h*)(ws + WMYH_O + off);
            v8h bml = *(const v8h*)(ws + WMYL_O + off);
            v8h bfh = *(const v8h*)(ws + WFFH_O + off);
            v8h bfl = *(const v8h*)(ws + WFFL_O + off);
            #pragma unroll
            for (int rt = 0; rt < 2; rt++){
                v8h ahi = *(const v8h*)&s_hm_hi[rt*16 + l15][q*32 + quad*8];
                v8h alo = *(const v8h*)&s_hm_lo[rt*16 + l15][q*32 + quad*8];
                prm[rt] = __builtin_amdgcn_mfma_f32_16x16x32_f16(ahi, bmh, prm[rt],0,0,0);
                prm[rt] = __builtin_amdgcn_mfma_f32_16x16x32_f16(ahi, bml, prm[rt],0,0,0);
                prm[rt] = __builtin_amdgcn_mfma_f32_16x16x32_f16(alo, bmh, prm[rt],0,0,0);
                prf[rt] = __builtin_amdgcn_mfma_f32_16x16x32_f16(ahi, bfh, prf[rt],0,0,0);
                prf[rt] = __builtin_amdgcn_mfma_f32_16x16x32_f16(ahi, bfl, prf[rt],0,0,0);
                prf[rt] = __builtin_amdgcn_mfma_f32_16x16x32_f16(alo, bfh, prf[rt],0,0,0);
            }
        }
        float bmv = b_my[ci*HH + jcol], bfv = b_ff[ci*HH + jcol];
        #pragma unroll
        for (int rt = 0; rt < 2; rt++){
            #pragma unroll
            for (int v = 0; v < 4; v++){
                pm_pk[ci][rt][v] = (f16)(prm[rt][v] + bmv);
                pf_pk[ci][rt][v] = (f16)(prf[rt][v] + bfv);
            }
        }
    }

    // ---- persistent register B-fragments: U_my all 4 ci; U_ff ci=0,1 ----
    v8h BUm[4][4], BUfr[2][4];
    #pragma unroll
    for (int ci = 0; ci < 4; ci++)
        #pragma unroll
        for (int q = 0; q < 4; q++)
            BUm[ci][q] = *(const v8h*)(ws + UMY_O + ((w*16 + ci*4 + q)*64 + lane)*8);
    #pragma unroll
    for (int ci = 0; ci < 2; ci++)
        #pragma unroll
        for (int q = 0; q < 4; q++)
            BUfr[ci][q] = *(const v8h*)(ws + UFF_O + ((w*16 + ci*4 + q)*64 + lane)*8);

    // head constants for this wave
    const int hch   = (w < 3) ? w : w - 3;
    const int hgc   = hch*16 + l15;
    const int hncol = (w < 3) ? 45 : 30;
    const int hrb   = (w < 3) ? 0 : 45;
    const int hwoff = (w < 3) ? w*2048 : 6144 + (w - 3)*2048;
    float hbias = 0.f;
    if (w < 5 && hgc < hncol) hbias = (w < 3) ? bh_my[hgc] : bh_ff[hgc];

    for (int t = 0; t < TT; t++){
        // =================== Phase A ===================
        float gv[5];
        if (t > 0 && tid < 128){
            int r = tid >> 2, g = tid & 3, b = row0 + r;
            const float* gp = gum + (((t-1)*4 + g)*BB + b)*KC;
            #pragma unroll
            for (int k = 0; k < KC; k++) gv[k] = gp[k];
        }
        float pv = 0.f; int pr = 0, pfld = 0;
        if (t > 0 && tid >= 128 && tid < 448){
            int idx = tid - 128;
            pr = idx / 10; pfld = idx % 10;
            int b = row0 + pr;
            if (pfld < 5)      pv = znorm[((t-1)*BB + b)*5 + pfld];
            else if (pfld == 5) pv = cond_m[(b*TT + t)*2 + 0];
            else if (pfld == 6) pv = cond_m[(b*TT + t)*2 + 1];
            else if (pfld == 7) pv = cond_y[b*TT + t];
            else if (pfld == 8) pv = cond_f[b*TT + t];
            else                pv = cond_fa[b*TT + t];
        }

        v4f zm[2][4], zf[2][4];
        #pragma unroll
        for (int ci = 0; ci < 4; ci++)
            #pragma unroll
            for (int rt = 0; rt < 2; rt++){
                zm[rt][ci] = (v4f){(float)pm_pk[ci][rt][0], (float)pm_pk[ci][rt][1],
                                   (float)pm_pk[ci][rt][2], (float)pm_pk[ci][rt][3]};
                zf[rt][ci] = (v4f){(float)pf_pk[ci][rt][0], (float)pf_pk[ci][rt][1],
                                   (float)pf_pk[ci][rt][2], (float)pf_pk[ci][rt][3]};
            }
        v4f hacc[2] = {(v4f){0,0,0,0}, (v4f){0,0,0,0}};

        #pragma unroll
        for (int q = 0; q < 4; q++){
            v8h bf2 = *(const v8h*)&s_uffB[(w*8 + q)*512 + lane*8];       // ci=2
            v8h bf3 = *(const v8h*)&s_uffB[(w*8 + 4 + q)*512 + lane*8];   // ci=3
            v8h bhv;
            if (w < 5) bhv = *(const v8h*)&s_wh[hwoff + q*512 + lane*8];
            #pragma unroll
            for (int rt = 0; rt < 2; rt++){
                v8h ahm = *(const v8h*)&s_hm_hi[rt*16 + l15][q*32 + quad*8];
                v8h alm = *(const v8h*)&s_hm_lo[rt*16 + l15][q*32 + quad*8];
                v8h ahf = *(const v8h*)&s_hf_hi[rt*16 + l15][q*32 + quad*8];
                v8h alf = *(const v8h*)&s_hf_lo[rt*16 + l15][q*32 + quad*8];
                zm[rt][0] = __builtin_amdgcn_mfma_f32_16x16x32_f16(ahm, BUm[0][q], zm[rt][0],0,0,0);
                zm[rt][1] = __builtin_amdgcn_mfma_f32_16x16x32_f16(ahm, BUm[1][q], zm[rt][1],0,0,0);
                zm[rt][2] = __builtin_amdgcn_mfma_f32_16x16x32_f16(ahm, BUm[2][q], zm[rt][2],0,0,0);
                zm[rt][3] = __builtin_amdgcn_mfma_f32_16x16x32_f16(ahm, BUm[3][q], zm[rt][3],0,0,0);
                zm[rt][0] = __builtin_amdgcn_mfma_f32_16x16x32_f16(alm, BUm[0][q], zm[rt][0],0,0,0);
                zm[rt][1] = __builtin_amdgcn_mfma_f32_16x16x32_f16(alm, BUm[1][q], zm[rt][1],0,0,0);
                zm[rt][2] = __builtin_amdgcn_mfma_f32_16x16x32_f16(alm, BUm[2][q], zm[rt][2],0,0,0);
                zm[rt][3] = __builtin_amdgcn_mfma_f32_16x16x32_f16(alm, BUm[3][q], zm[rt][3],0,0,0);
                zf[rt][0] = __builtin_amdgcn_mfma_f32_16x16x32_f16(ahf, BUfr[0][q], zf[rt][0],0,0,0);
                zf[rt][1] = __builtin_amdgcn_mfma_f32_16x16x32_f16(ahf, BUfr[1][q], zf[rt][1],0,0,0);
                zf[rt][2] = __builtin_amdgcn_mfma_f32_16x16x32_f16(ahf, bf2,        zf[rt][2],0,0,0);
                zf[rt][3] = __builtin_amdgcn_mfma_f32_16x16x32_f16(ahf, bf3,        zf[rt][3],0,0,0);
                zf[rt][0] = __builtin_amdgcn_mfma_f32_16x16x32_f16(alf, BUfr[0][q], zf[rt][0],0,0,0);
                zf[rt][1] = __builtin_amdgcn_mfma_f32_16x16x32_f16(alf, BUfr[1][q], zf[rt][1],0,0,0);
                zf[rt][2] = __builtin_amdgcn_mfma_f32_16x16x32_f16(alf, bf2,        zf[rt][2],0,0,0);
                zf[rt][3] = __builtin_amdgcn_mfma_f32_16x16x32_f16(alf, bf3,        zf[rt][3],0,0,0);
                if (w < 5 && t > 0)
                    hacc[rt] = __builtin_amdgcn_mfma_f32_16x16x32_f16(
                        (w < 3) ? ahm : ahf, bhv, hacc[rt],0,0,0);
            }
        }
        if (w < 5 && t > 0 && hgc < hncol){
            #pragma unroll
            for (int rt = 0; rt < 2; rt++)
                #pragma unroll
                for (int v = 0; v < 4; v++)
                    s_r[rt*16 + quad*4 + v][hrb + hgc] = hacc[rt][v] + hbias;
        }
        if (t > 0 && tid >= 128 && tid < 448) s_znc[pr][pfld] = pv;
        __syncthreads();

        // =================== Phase B: softmax + sample + clip (step t-1) ===================
        if (t > 0 && tid < 128){
            int r = tid >> 2, g = tid & 3;
            int base = (g==0) ? 0 : (g==1) ? 30 : (g==2) ? 45 : 60;
            const float* Rr = s_r[r];
            float l0 = Rr[base], l1 = Rr[base+1], l2 = Rr[base+2], l3 = Rr[base+3], l4 = Rr[base+4];
            float m = fmaxf(fmaxf(fmaxf(l0,l1), fmaxf(l2,l3)), l4);
            float s = __expf(l0-m)+__expf(l1-m)+__expf(l2-m)+__expf(l3-m)+__expf(l4-m);
            s_red[r][2*g] = m; s_red[r][2*g+1] = 1.0f / s;
            int idx = 0; float bv = l0 + gv[0];
            { float v1 = l1+gv[1]; if (v1>bv){bv=v1;idx=1;}
              float v2 = l2+gv[2]; if (v2>bv){bv=v2;idx=2;}
              float v3 = l3+gv[3]; if (v3>bv){bv=v3;idx=3;}
              float v4 = l4+gv[4]; if (v4>bv){bv=v4;idx=4;} }
            float mu = Rr[base+5+idx], sd = __expf(Rr[base+10+idx]);
            if (g == 0){
                float z1 = s_znc[r][0], z2 = s_znc[r][1];
                float rv = tanh_(Rr[25+idx]);
                float slon = mu + sd*z1;
                float slat = Rr[15+idx] + __expf(Rr[20+idx]) *
                             (rv*z1 + sqrtf(fmaxf(0.f, 1.f - rv*rv))*z2);
                float nm0 = s_znc[r][5], nm1 = s_znc[r][6];
                s_c5[r][0] = (fabsf(slon-nm0) < AM0) ? slon : nm0;
                s_c5[r][1] = (fabsf(slat-nm1) < AM1) ? slat : nm1;
            } else {
                float zz = s_znc[r][1+g];
                float sv = mu + sd*zz;
                float nv = s_znc[r][6+g];
                float cv = (fabsf(sv-nv) < AO) ? sv : nv;
                if (g == 1) s_c5[r][2] = cv;
                else if (g == 2){ s_c5[r][3] = cv; s_c2[r][0] = cv; }
                else            { s_c5[r][4] = cv; s_c2[r][1] = cv; }
            }
        }
        __syncthreads();

        // =================== Phase C: gates(t) + outputs(t-1) ===================
        {
            float wm[5][4], wf2[2][4];
            #pragma unroll
            for (int k = 0; k < 5; k++)
                #pragma unroll
                for (int g = 0; g < 4; g++) wm[k][g] = s_wcm[k][g*HH + jcol];
            #pragma unroll
            for (int k = 0; k < 2; k++)
                #pragma unroll
                for (int g = 0; g < 4; g++) wf2[k][g] = s_wcf[k][g*HH + jcol];

            #pragma unroll
            for (int rt = 0; rt < 2; rt++)
                #pragma unroll
                for (int v = 0; v < 4; v++){
                    int row = rt*16 + quad*4 + v;
                    float z0 = zm[rt][0][v], z1 = zm[rt][1][v], z2 = zm[rt][2][v], z3 = zm[rt][3][v];
                    #pragma unroll
                    for (int k = 0; k < 5; k++){
                        float cv = s_c5[row][k];
                        z0 = fmaf(cv, wm[k][0], z0);
                        z1 = fmaf(cv, wm[k][1], z1);
                        z2 = fmaf(cv, wm[k][2], z2);
                        z3 = fmaf(cv, wm[k][3], z3);
                    }
                    float c2 = sigm(z1)*c_my[rt*4+v] + sigm(z0)*tanh_(z2);
                    c_my[rt*4+v] = c2;
                    float h = sigm(z3)*tanh_(c2);
                    f16 hi = (f16)h;
                    s_hm_hi[row][jcol] = hi;
                    s_hm_lo[row][jcol] = (f16)(h - (float)hi);

                    float y0 = zf[rt][0][v], y1 = zf[rt][1][v], y2 = zf[rt][2][v], y3 = zf[rt][3][v];
                    #pragma unroll
                    for (int k = 0; k < 2; k++){
                        float cv = s_c2[row][k];
                        y0 = fmaf(cv, wf2[k][0], y0);
                        y1 = fmaf(cv, wf2[k][1], y1);
                        y2 = fmaf(cv, wf2[k][2], y2);
                        y3 = fmaf(cv, wf2[k][3], y3);
                    }
                    float d2 = sigm(y1)*c_ff[rt*4+v] + sigm(y0)*tanh_(y2);
                    c_ff[rt*4+v] = d2;
                    float hf = sigm(y3)*tanh_(d2);
                    f16 hif = (f16)hf;
                    s_hf_hi[row][jcol] = hif;
                    s_hf_lo[row][jcol] = (f16)(hf - (float)hif);
                }
        }

        if (t > 0){
            int tp = t - 1;
            for (int idx = tid; idx < R*75; idx += NT){
                int r = idx / 75, q = idx % 75;
                int b = row0 + r;
                float v; int dst;
                if (q < 30){
                    float x = s_r[r][q];
                    if (q < 5)       v = __expf(x - s_red[r][0]) * s_red[r][1];
                    else if (q < 10) v = x;
                    else if (q < 15) v = __expf(x);
                    else if (q < 20) v = x;
                    else if (q < 25) v = __expf(x);
                    else             v = tanh_(x);
                    dst = (b*TT + tp)*30 + q;
                } else if (q < 45){
                    int q2 = q - 30; float x = s_r[r][30 + q2];
                    v = (q2 < 5) ? __expf(x - s_red[r][2]) * s_red[r][3]
                                 : (q2 < 10) ? x : __expf(x);
                    dst = GY_OFF + (b*TT + tp)*15 + q2;
                } else if (q < 60){
                    int q2 = q - 45; float x = s_r[r][45 + q2];
                    v = (q2 < 5) ? __expf(x - s_red[r][4]) * s_red[r][5]
                                 : (q2 < 10) ? x : __expf(x);
                    dst = GF_OFF + (b*TT + tp)*15 + q2;
                } else {
                    int q2 = q - 60; float x = s_r[r][60 + q2];
                    v = (q2 < 5) ? __expf(x - s_red[r][6]) * s_red[r][7]
                                 : (q2 < 10) ? x : __expf(x);
                    dst = GFA_OFF + (b*TT + tp)*15 + q2;
                }
                out[dst] = v;
            }
        }
        __syncthreads();
    }

    // =================== Epilogue: heads(TT-1) + softmax + outputs ===================
    {
        v4f hacc[2] = {(v4f){0,0,0,0}, (v4f){0,0,0,0}};
        if (w < 5){
            #pragma unroll
            for (int q = 0; q < 4; q++){
                v8h bhv = *(const v8h*)&s_wh[hwoff + q*512 + lane*8];
                #pragma unroll
                for (int rt = 0; rt < 2; rt++){
                    v8h a = (w < 3) ? *(const v8h*)&s_hm_hi[rt*16 + l15][q*32 + quad*8]
                                    : *(const v8h*)&s_hf_hi[rt*16 + l15][q*32 + quad*8];
                    hacc[rt] = __builtin_amdgcn_mfma_f32_16x16x32_f16(a, bhv, hacc[rt],0,0,0);
                }
            }
            if (hgc < hncol){
                #pragma unroll
                for (int rt = 0; rt < 2; rt++)
                    #pragma unroll
                    for (int v = 0; v < 4; v++)
                        s_r[rt*16 + quad*4 + v][hrb + hgc] = hacc[rt][v] + hbias;
            }
        }
        __syncthreads();
        if (tid < 128){
            int r = tid >> 2, g = tid & 3;
            int base = (g==0) ? 0 : (g==1) ? 30 : (g==2) ? 45 : 60;
            float m = s_r[r][base];
            #pragma unroll
            for (int k = 1; k < KC; k++) m = fmaxf(m, s_r[r][base+k]);
            float s = 0.f;
            #pragma unroll
            for (int k = 0; k < KC; k++) s += __expf(s_r[r][base+k] - m);
            s_red[r][2*g] = m; s_red[r][2*g+1] = 1.0f / s;
        }
        __syncthreads();
        int tp = TT - 1;
        for (int idx = tid; idx < R*75; idx += NT){
            int r = idx / 75, q = idx % 75;
            int b = row0 + r;
            float v; int dst;
            if (q < 30){
                float x = s_r[r][q];
                if (q < 5)       v = __expf(x - s_red[r][0]) * s_red[r][1];
                else if (q < 10) v = x;
                else if (q < 15) v = __expf(x);
                else if (q < 20) v = x;
                else if (q < 25) v = __expf(x);
                else             v = tanh_(x);
                dst = (b*TT + tp)*30 + q;
            } else if (q < 45){
                int q2 = q - 30; float x = s_r[r][30 + q2];
                v = (q2 < 5) ? __expf(x - s_red[r][2]) * s_red[r][3]
                             : (q2 < 10) ? x : __expf(x);
                dst = GY_OFF + (b*TT + tp)*15 + q2;
            } else if (q < 60){
                int q2 = q - 45; float x = s_r[r][45 + q2];
                v = (q2 < 5) ? __expf(x - s_red[r][4]) * s_red[r][5]
                             : (q2 < 10) ? x : __expf(x);
                dst = GF_OFF + (b*TT + tp)*15 + q2;
            } else {
                int q2 = q - 60; float x = s_r[r][60 + q2];
                v = (q2 < 5) ? __expf(x - s_red[r][6]) * s_red[r][7]
                             : (q2 < 10) ? x : __expf(x);
                dst = GFA_OFF + (b*TT + tp)*15 + q2;
            }
            out[dst] = v;
        }
    }
}

extern "C" void kernel_launch(void* const* d_in, const int* in_sizes, int n_in,
                              void* d_out, int out_size, void* d_ws, size_t ws_size,
                              hipStream_t stream)
{
    (void)in_sizes; (void)n_in; (void)ws_size; (void)out_size;
    const float* cond_m  = (const float*)d_in[0];
    const float* cond_y  = (const float*)d_in[1];
    const float* cond_f  = (const float*)d_in[2];
    const float* cond_fa = (const float*)d_in[3];
    const float* state_h = (const float*)d_in[4];
    const float* state_c = (const float*)d_in[5];
    const float* W_my    = (const float*)d_in[6];
    const float* U_my    = (const float*)d_in[7];
    const float* b_my    = (const float*)d_in[8];
    const float* W_ff    = (const float*)d_in[9];
    const float* U_ff    = (const float*)d_in[10];
    const float* b_ff    = (const float*)d_in[11];
    const float* Wh_my   = (const float*)d_in[12];
    const float* bh_my   = (const float*)d_in[13];
    const float* Wh_ff   = (const float*)d_in[14];
    const float* bh_ff   = (const float*)d_in[15];
    const float* gum     = (const float*)d_in[16];
    const float* znorm   = (const float*)d_in[17];
    f16* ws = (f16*)d_ws;
    float* out = (float*)d_out;

    prep_kernel<<<(PREP_N + 255)/256, 256, 0, stream>>>(U_my, U_ff, W_my, W_ff, Wh_my, Wh_ff, ws);
    decoder_kernel<<<NBLK, NT, 0, stream>>>(
        cond_m, cond_y, cond_f, cond_fa, state_h, state_c,
        W_my, b_my, W_ff, b_ff, bh_my, bh_ff, gum, znorm, ws, out);
}